// Round 9
// baseline (279.154 us; speedup 1.0000x reference)
//
#include <hip/hip_runtime.h>
#include <hip/hip_bf16.h>

typedef unsigned short u16;
typedef __attribute__((ext_vector_type(8))) short s16x8;   // 8 bf16 (4 VGPRs) MFMA A/B frag
typedef __attribute__((ext_vector_type(4))) float f32x4;   // MFMA C/D frag

__device__ __forceinline__ u16 f2bf(float f) {
  union { float f; unsigned u; } v; v.f = f;
  unsigned r = (v.u + 0x7fffu + ((v.u >> 16) & 1u)) >> 16;  // RNE
  return (u16)r;
}
__device__ __forceinline__ float bf2f(u16 u) {
  union { unsigned u; float f; } v; v.u = ((unsigned)u) << 16;
  return v.f;
}
__device__ __forceinline__ void gld_lds16(const void* g, void* l) {
  __builtin_amdgcn_global_load_lds(
      (const __attribute__((address_space(1))) void*)g,
      (__attribute__((address_space(3))) void*)l, 16, 0, 0);
}
// inline-asm ds_read_b128 (numerics proven in R7); pair with lgkmcnt(0)+sched_barrier(0) (rule 18)
__device__ __forceinline__ s16x8 dsr128(const u16* p) {
  s16x8 r;
  asm volatile("ds_read_b128 %0, %1"
               : "=v"(r)
               : "v"((const __attribute__((address_space(3))) u16*)p));
  return r;
}

// ---------------- weight prep: Wkv bf16 [1024][512], WqT bf16 [512(c)][512(hd)], Wout bf16 [512][512]
__global__ void prep_w(const float* __restrict__ Wqkv, const float* __restrict__ Woutf,
                       u16* __restrict__ Wkv, u16* __restrict__ WqT, u16* __restrict__ Wout) {
  int i = blockIdx.x * 256 + threadIdx.x;          // grid 2048*256 = 524288
  Wkv[i] = f2bf(Wqkv[262144 + i]);                 // rows 512..1535 of W_qkv (k then v)
  if (i < 262144) {
    int c = i >> 9, o = i & 511;
    WqT[i]  = f2bf(Wqkv[o * 512 + c]);             // WqT[c][hd] = Wq[hd][c]
    Wout[i] = f2bf(Woutf[i]);
  }
}

// ---------------- x transpose+convert: x[b][c][l] f32 -> xt[b][l][c] bf16
__global__ __launch_bounds__(256) void prep_x(const float* __restrict__ x, u16* __restrict__ xt) {
  __shared__ float t[32][33];
  int l0 = blockIdx.x * 32, c0 = blockIdx.y * 32;
  size_t b = blockIdx.z;
  int tid = threadIdx.x;
  int r = tid >> 3, q = tid & 7;
  const float4 v = *(const float4*)(x + (b * 512 + c0 + r) * 8192 + l0 + q * 4);
  t[r][q * 4 + 0] = v.x; t[r][q * 4 + 1] = v.y;
  t[r][q * 4 + 2] = v.z; t[r][q * 4 + 3] = v.w;
  __syncthreads();
  ushort4 o;
  o.x = f2bf(t[q * 4 + 0][r]); o.y = f2bf(t[q * 4 + 1][r]);
  o.z = f2bf(t[q * 4 + 2][r]); o.w = f2bf(t[q * 4 + 3][r]);
  *(ushort4*)(xt + (b * 8192 + l0 + r) * 512 + c0 + q * 4) = o;
}

// ---------------- small-GEMM (m97-style 128x128, BK=32, linear LDS): bf16 out
__global__ __launch_bounds__(256) void gemm_bt(
    const u16* __restrict__ A, size_t sA,
    const u16* __restrict__ BT, size_t sB,
    u16* __restrict__ Cv, size_t sC,
    int N, int K)
{
  __shared__ u16 lsa[128 * 32];
  __shared__ u16 lsb[128 * 32];
  int tid = threadIdx.x, wid = tid >> 6, lane = tid & 63;
  int m0 = blockIdx.y << 7, n0 = blockIdx.x << 7;
  const u16* Ab = A + (size_t)blockIdx.z * sA;
  const u16* Bb = BT + (size_t)blockIdx.z * sB;
  int fr = lane & 15, kg = lane >> 4;
  int wr = wid >> 1, wc = wid & 1;
  int f0 = tid, f1 = tid + 256;
  const u16* pA0 = Ab + (size_t)(m0 + (f0 >> 2)) * K + (f0 & 3) * 8;
  const u16* pA1 = Ab + (size_t)(m0 + (f1 >> 2)) * K + (f1 & 3) * 8;
  const u16* pB0 = Bb + (size_t)(n0 + (f0 >> 2)) * K + (f0 & 3) * 8;
  const u16* pB1 = Bb + (size_t)(n0 + (f1 >> 2)) * K + (f1 & 3) * 8;
  u16* dA0 = &lsa[wid * 512];
  u16* dA1 = &lsa[(wid + 4) * 512];
  u16* dB0 = &lsb[wid * 512];
  u16* dB1 = &lsb[(wid + 4) * 512];
  f32x4 acc[4][4] = {};
  for (int kt = 0; kt < K; kt += 32) {
    gld_lds16(pA0, dA0); gld_lds16(pA1, dA1);
    gld_lds16(pB0, dB0); gld_lds16(pB1, dB1);
    pA0 += 32; pA1 += 32; pB0 += 32; pB1 += 32;
    __syncthreads();
    s16x8 af[4], bf_[4];
#pragma unroll
    for (int mi = 0; mi < 4; ++mi)
      af[mi] = *(const s16x8*)&lsa[(wr * 64 + mi * 16 + fr) * 32 + kg * 8];
#pragma unroll
    for (int ni = 0; ni < 4; ++ni)
      bf_[ni] = *(const s16x8*)&lsb[(wc * 64 + ni * 16 + fr) * 32 + kg * 8];
#pragma unroll
    for (int mi = 0; mi < 4; ++mi)
#pragma unroll
      for (int ni = 0; ni < 4; ++ni)
        acc[mi][ni] = __builtin_amdgcn_mfma_f32_16x16x32_bf16(af[mi], bf_[ni], acc[mi][ni], 0, 0, 0);
    __syncthreads();
  }
  int r0 = m0 + wr * 64 + kg * 4;
  int c0 = n0 + wc * 64 + fr;
  u16* C = Cv + (size_t)blockIdx.z * sC;
#pragma unroll
  for (int mi = 0; mi < 4; ++mi)
#pragma unroll
    for (int ni = 0; ni < 4; ++ni)
#pragma unroll
      for (int j = 0; j < 4; ++j)
        C[(size_t)(r0 + mi * 16 + j) * N + (c0 + ni * 16)] = f2bf(acc[mi][ni][j]);
}

// ---------------- 128x128 GEMM v2: dbuf LDS + counted vmcnt + conflict-free swizzle ----------------
// C[m][n] = sum_k A[m][k]*BT[n][k], K=512, strides 512, C-stride 8192.  4 waves, BK=32,
// LDS 2x(8KB A + 8KB B) = 32 KB -> 3+ blocks/CU.
// Swizzle (verified 0 conflicts, R6): within each 128B double-row b2 (rows 2*b2,2*b2+1),
// logical (local row rl, 16B-chunk q) stored at phys slot (rl*4 + q + b2) & 7.
// Staging: linear gld_lds dest, inverse-permuted global src (rule 21).
// vmcnt accounting (R8 bug fixed): stage() = 4 loads/tile, steady state 8 in flight
// (tile k + k+1) -> vmcnt(4) drains exactly the oldest 4 = tile k.  Tail: vmcnt(0).
template <int OUTF>
__global__ __launch_bounds__(256, 3) void gemm128(
    const u16* __restrict__ A, size_t sA,
    const u16* __restrict__ BT, size_t sB,
    void* __restrict__ Cv, size_t sC,
    const float* __restrict__ bias,
    int Mt, int Nt)
{
  __shared__ u16 lsa[2][4096];
  __shared__ u16 lsb[2][4096];
  const int tid = threadIdx.x, wid = tid >> 6, lane = tid & 63;
  const int fr = lane & 15, kg = lane >> 4;
  const int wr = wid >> 1, wc = wid & 1;

  // T1: bijective XCD chunk swizzle (nwg % 8 == 0), M fastest -> same-XCD blocks share B panel
  const int nwg = (int)gridDim.x;
  const int bx = (int)blockIdx.x;
  const int id = (bx & 7) * (nwg >> 3) + (bx >> 3);
  const int my = id % Mt;
  const int t2 = id / Mt;
  const int nx = t2 % Nt;
  const int z  = t2 / Nt;
  const int m0 = my << 7, n0 = nx << 7;
  const u16* Ab = A + (size_t)z * sA;
  const u16* Bb = BT + (size_t)z * sB;

  // staging: thread covers phys 16B-chunks P0 = tid, P1 = tid+256 (512 chunks per 8KB tile).
  // phys chunk P: double-row b2 = P>>3, slot s = P&7 holds t = (s-b2)&7:
  //   row = b2*2 + (t>>2), within-row chunk = t&3.
  const int P0 = tid, P1 = tid + 256;
  int b2_, s_, t_;
  b2_ = P0 >> 3; s_ = P0 & 7; t_ = (s_ - b2_) & 7;
  const size_t g0 = (size_t)((b2_ << 1) + (t_ >> 2)) * 512 + (t_ & 3) * 8;
  b2_ = P1 >> 3; s_ = P1 & 7; t_ = (s_ - b2_) & 7;
  const size_t g1 = (size_t)((b2_ << 1) + (t_ >> 2)) * 512 + (t_ & 3) * 8;
  const u16* paG0 = Ab + (size_t)m0 * 512 + g0;
  const u16* paG1 = Ab + (size_t)m0 * 512 + g1;
  const u16* pbG0 = Bb + (size_t)n0 * 512 + g0;
  const u16* pbG1 = Bb + (size_t)n0 * 512 + g1;

  // frag LDS offsets (halves): row r, k-chunk kg -> (r>>1)*64 + (((r&1)*4 + kg + (r>>1))&7)*8
  int aoff[4], boff[4];
#pragma unroll
  for (int i = 0; i < 4; ++i) {
    int ra = wr * 64 + i * 16 + fr;
    aoff[i] = (ra >> 1) * 64 + ((((ra & 1) << 2) + kg + (ra >> 1)) & 7) * 8;
    int rb = wc * 64 + i * 16 + fr;
    boff[i] = (rb >> 1) * 64 + ((((rb & 1) << 2) + kg + (rb >> 1)) & 7) * 8;
  }

  auto stage = [&](int sl, int kt) {
    gld_lds16(paG0 + kt, &lsa[sl][P0 * 8]);
    gld_lds16(paG1 + kt, &lsa[sl][P1 * 8]);
    gld_lds16(pbG0 + kt, &lsb[sl][P0 * 8]);
    gld_lds16(pbG1 + kt, &lsb[sl][P1 * 8]);
  };

  f32x4 acc[4][4] = {};
  stage(0, 0);                                   // prologue: 4 loads outstanding
#pragma unroll
  for (int k = 0; k < 16; ++k) {
    if (k < 15) stage((k + 1) & 1, (k + 1) * 32);   // issue next tile first (4 more in flight)
    if (k < 15) { asm volatile("s_waitcnt vmcnt(4)" ::: "memory"); }  // oldest 4 = tile k landed
    else        { asm volatile("s_waitcnt vmcnt(0)" ::: "memory"); }
    __builtin_amdgcn_s_barrier();                   // stage(k) visible to all waves
    s16x8 af[4], bf_[4];
    const u16* la = lsa[k & 1];
    const u16* lb = lsb[k & 1];
#pragma unroll
    for (int mi = 0; mi < 4; ++mi) af[mi] = dsr128(la + aoff[mi]);
#pragma unroll
    for (int ni = 0; ni < 4; ++ni) bf_[ni] = dsr128(lb + boff[ni]);
    asm volatile("s_waitcnt lgkmcnt(0)" ::: "memory");
    __builtin_amdgcn_sched_barrier(0);
    __builtin_amdgcn_s_setprio(1);
#pragma unroll
    for (int mi = 0; mi < 4; ++mi)
#pragma unroll
      for (int ni = 0; ni < 4; ++ni)
        acc[mi][ni] = __builtin_amdgcn_mfma_f32_16x16x32_bf16(af[mi], bf_[ni], acc[mi][ni], 0, 0, 0);
    __builtin_amdgcn_s_setprio(0);
    __builtin_amdgcn_s_barrier();                   // done reading buf[k&1]; iter k+1 may stage k+2 into it
  }

  // epilogue: C/D frag layout col = lane&15, row = (lane>>4)*4 + j
  const int r0 = m0 + wr * 64 + kg * 4;
  const int c0 = n0 + wc * 64 + fr;
  if (OUTF == 0) {
    u16* C = (u16*)Cv + (size_t)z * sC;
#pragma unroll
    for (int mi = 0; mi < 4; ++mi)
#pragma unroll
      for (int ni = 0; ni < 4; ++ni)
#pragma unroll
        for (int j = 0; j < 4; ++j)
          C[(size_t)(r0 + mi * 16 + j) * 8192 + (c0 + ni * 16)] = f2bf(acc[mi][ni][j]);
  } else {
    float* C = (float*)Cv + (size_t)z * sC;
#pragma unroll
    for (int mi = 0; mi < 4; ++mi)
#pragma unroll
      for (int j = 0; j < 4; ++j) {
        float bv = bias[r0 + mi * 16 + j];
#pragma unroll
        for (int ni = 0; ni < 4; ++ni)
          C[(size_t)(r0 + mi * 16 + j) * 8192 + (c0 + ni * 16)] = acc[mi][ni][j] + bv;
      }
  }
}

// ---------------- context partials: per (split s, h, b): atomically accumulate
// E[b][h][d][e] += exp(k) @ v^T over L-slice, Z[b][h][d] += rowsum(exp(k))
#define NSPLIT 16
#define SLICE  512   // 8192 / NSPLIT
__global__ __launch_bounds__(256) void ctx_partial(const u16* __restrict__ kv,
                                                   float* __restrict__ E, float* __restrict__ Z) {
  int s = blockIdx.x, h = blockIdx.y, b = blockIdx.z;
  int tid = threadIdx.x, wid = tid >> 6, lane = tid & 63;
  int fr = lane & 15, kg = lane >> 4;
  const u16* kbase = kv + ((size_t)b * 1024 + h * 64) * 8192;          // k rows
  const u16* vbase = kbase + (size_t)512 * 8192;                        // v rows
  int d = wid * 16 + fr;                                                // A-frag row for this lane
  const u16* krow = kbase + (size_t)d * 8192 + s * SLICE + kg * 8;
  f32x4 acc[4] = {};
  float z = 0.f;
  for (int l = 0; l < SLICE; l += 32) {
    s16x8 kf = *(const s16x8*)(krow + l);
    s16x8 pf;
#pragma unroll
    for (int j = 0; j < 8; ++j) {
      float p = __expf(bf2f((u16)kf[j]));   // no max-subtraction: |k| <~ 6, exp safe in fp32
      z += p;
      pf[j] = (short)f2bf(p);
    }
#pragma unroll
    for (int ni = 0; ni < 4; ++ni) {
      int e = ni * 16 + fr;
      const s16x8 vf = *(const s16x8*)(vbase + (size_t)e * 8192 + s * SLICE + kg * 8 + l);
      acc[ni] = __builtin_amdgcn_mfma_f32_16x16x32_bf16(pf, vf, acc[ni], 0, 0, 0);
    }
  }
  z += __shfl_xor(z, 16);
  z += __shfl_xor(z, 32);
  size_t bh = (size_t)(b * 8 + h);
  if (kg == 0) atomicAdd(&Z[bh * 64 + d], z);
  float* Eb = E + bh * 4096;
#pragma unroll
  for (int ni = 0; ni < 4; ++ni)
#pragma unroll
    for (int j = 0; j < 4; ++j)
      atomicAdd(&Eb[(wid * 16 + kg * 4 + j) * 64 + ni * 16 + fr], acc[ni][j]);  // C/D: col=l&15, row=(l>>4)*4+j
}

// ---------------- normalize ctx + M1[b][c][h*64+d] = sum_e Wout[c][h*64+e]*ctx[d][e]
__global__ __launch_bounds__(256) void m1_fused(const float* __restrict__ E, const float* __restrict__ Z,
                                                const u16* __restrict__ Wout, u16* __restrict__ M1) {
  int cb = blockIdx.x, h = blockIdx.y, b = blockIdx.z;
  __shared__ float ctx[64][65];
  __shared__ float zs[64];
  int tid = threadIdx.x;
  size_t bh = (size_t)(b * 8 + h);
  const float* Eb = E + bh * 4096;
  if (tid < 64) zs[tid] = Z[bh * 64 + tid];
  __syncthreads();
  for (int i = tid; i < 4096; i += 256)
    ctx[i >> 6][i & 63] = Eb[i] / zs[i >> 6];
  __syncthreads();
  int d = tid & 63;
  int hbase = h * 64;
  for (int ci = 0; ci < 16; ++ci) {
    int c = __builtin_amdgcn_readfirstlane(cb * 64 + (tid >> 6) + ci * 4);  // wave-uniform -> SGPR
    const u16* wrow = Wout + c * 512 + hbase;
    float a0 = 0.f, a1 = 0.f, a2 = 0.f, a3 = 0.f;
#pragma unroll
    for (int e = 0; e < 64; e += 4) {
      a0 += bf2f(wrow[e + 0]) * ctx[d][e + 0];
      a1 += bf2f(wrow[e + 1]) * ctx[d][e + 1];
      a2 += bf2f(wrow[e + 2]) * ctx[d][e + 2];
      a3 += bf2f(wrow[e + 3]) * ctx[d][e + 3];
    }
    M1[((size_t)b * 512 + c) * 512 + hbase + d] = f2bf((a0 + a1) + (a2 + a3));
  }
}

extern "C" void kernel_launch(void* const* d_in, const int* in_sizes, int n_in,
                              void* d_out, int out_size, void* d_ws, size_t ws_size,
                              hipStream_t stream) {
  const float* x     = (const float*)d_in[0];   // [8,512,8192]
  const float* Wqkv  = (const float*)d_in[1];   // [1536,512]
  const float* Woutf = (const float*)d_in[2];   // [512,512]
  const float* bout  = (const float*)d_in[3];   // [512]
  char* ws = (char*)d_ws;
  u16*  xt  = (u16*)ws;                          //  64 MB  xt[b][l][c] bf16
  u16*  kv  = (u16*)(ws + 67108864);             // 128 MB  kv[b][o<1024][l] bf16 (k rows 0..511, v rows 512..1023)
  u16*  Wkv = (u16*)(ws + 201326592);            //   1 MB
  u16*  WqT = (u16*)(ws + 202375168);            // 0.5 MB
  u16*  Wo  = (u16*)(ws + 202899456);            // 0.5 MB
  u16*  M1  = (u16*)(ws + 203423744);            //   4 MB
  u16*  G   = (u16*)(ws + 207618048);            //   4 MB
  float* E  = (float*)(ws + 211812352);          //   1 MB  E[b][h][64][64] f32 (atomic-accumulated)
  float* Z  = (float*)(ws + 212860928);          //  16 KB  Z[b][h][64] f32

  hipMemsetAsync(ws + 211812352, 0, 1048576 + 16384, stream);  // zero E+Z (ws not re-poisoned between replays)
  prep_w<<<2048, 256, 0, stream>>>(Wqkv, Woutf, Wkv, WqT, Wo);
  prep_x<<<dim3(256, 16, 8), 256, 0, stream>>>(x, xt);
  // kv[b] = Wkv @ x[b] : M=1024, N=8192, K=512  (grid = Mt*Nt*B = 8*64*8 = 4096)
  gemm128<0><<<4096, 256, 0, stream>>>(Wkv, 0, xt, (size_t)8192 * 512,
                                       kv, (size_t)1024 * 8192, nullptr, 8, 64);
  ctx_partial<<<dim3(NSPLIT, 8, 8), 256, 0, stream>>>(kv, E, Z);
  m1_fused<<<dim3(8, 8, 8), 256, 0, stream>>>(E, Z, Wo, M1);
  // G[b] = M1[b] @ Wq : M=512, N=512, K=512   (small: old 128² kernel)
  gemm_bt<<<dim3(4, 4, 8), 256, 0, stream>>>(M1, (size_t)512 * 512, WqT, 0,
                                             G, (size_t)512 * 512, 512, 512);
  // out[b] = G[b] @ x[b] + b_out : M=512, N=8192, K=512, f32 out + bias  (grid = 4*64*8 = 2048)
  gemm128<1><<<2048, 256, 0, stream>>>(G, (size_t)512 * 512, xt, (size_t)8192 * 512,
                                       d_out, (size_t)512 * 8192, bout, 4, 64);
}

// Round 10
// 271.869 us; speedup vs baseline: 1.0268x; 1.0268x over previous
//
#include <hip/hip_runtime.h>
#include <hip/hip_bf16.h>

typedef unsigned short u16;
typedef __attribute__((ext_vector_type(8))) short s16x8;   // 8 bf16 (4 VGPRs) MFMA A/B frag
typedef __attribute__((ext_vector_type(4))) float f32x4;   // MFMA C/D frag

__device__ __forceinline__ u16 f2bf(float f) {
  union { float f; unsigned u; } v; v.f = f;
  unsigned r = (v.u + 0x7fffu + ((v.u >> 16) & 1u)) >> 16;  // RNE
  return (u16)r;
}
__device__ __forceinline__ float bf2f(u16 u) {
  union { unsigned u; float f; } v; v.u = ((unsigned)u) << 16;
  return v.f;
}
__device__ __forceinline__ void gld_lds16(const void* g, void* l) {
  __builtin_amdgcn_global_load_lds(
      (const __attribute__((address_space(1))) void*)g,
      (__attribute__((address_space(3))) void*)l, 16, 0, 0);
}
// inline-asm ds_read_b128 (numerics proven in R7); pair with lgkmcnt(0)+sched_barrier(0) (rule 18)
__device__ __forceinline__ s16x8 dsr128(const u16* p) {
  s16x8 r;
  asm volatile("ds_read_b128 %0, %1"
               : "=v"(r)
               : "v"((const __attribute__((address_space(3))) u16*)p));
  return r;
}

// ---------------- weight prep: Wkv bf16 [1024][512], WqT bf16 [512(c)][512(hd)], Wout bf16 [512][512]
__global__ void prep_w(const float* __restrict__ Wqkv, const float* __restrict__ Woutf,
                       u16* __restrict__ Wkv, u16* __restrict__ WqT, u16* __restrict__ Wout) {
  int i = blockIdx.x * 256 + threadIdx.x;          // grid 2048*256 = 524288
  Wkv[i] = f2bf(Wqkv[262144 + i]);                 // rows 512..1535 of W_qkv (k then v)
  if (i < 262144) {
    int c = i >> 9, o = i & 511;
    WqT[i]  = f2bf(Wqkv[o * 512 + c]);             // WqT[c][hd] = Wq[hd][c]
    Wout[i] = f2bf(Woutf[i]);
  }
}

// ---------------- x transpose+convert: x[b][c][l] f32 -> xt[b][l][c] bf16
__global__ __launch_bounds__(256) void prep_x(const float* __restrict__ x, u16* __restrict__ xt) {
  __shared__ float t[32][33];
  int l0 = blockIdx.x * 32, c0 = blockIdx.y * 32;
  size_t b = blockIdx.z;
  int tid = threadIdx.x;
  int r = tid >> 3, q = tid & 7;
  const float4 v = *(const float4*)(x + (b * 512 + c0 + r) * 8192 + l0 + q * 4);
  t[r][q * 4 + 0] = v.x; t[r][q * 4 + 1] = v.y;
  t[r][q * 4 + 2] = v.z; t[r][q * 4 + 3] = v.w;
  __syncthreads();
  ushort4 o;
  o.x = f2bf(t[q * 4 + 0][r]); o.y = f2bf(t[q * 4 + 1][r]);
  o.z = f2bf(t[q * 4 + 2][r]); o.w = f2bf(t[q * 4 + 3][r]);
  *(ushort4*)(xt + (b * 8192 + l0 + r) * 512 + c0 + q * 4) = o;
}

// ---------------- small-GEMM (m97-style 128x128, BK=32, linear LDS): bf16 out
__global__ __launch_bounds__(256) void gemm_bt(
    const u16* __restrict__ A, size_t sA,
    const u16* __restrict__ BT, size_t sB,
    u16* __restrict__ Cv, size_t sC,
    int N, int K)
{
  __shared__ u16 lsa[128 * 32];
  __shared__ u16 lsb[128 * 32];
  int tid = threadIdx.x, wid = tid >> 6, lane = tid & 63;
  int m0 = blockIdx.y << 7, n0 = blockIdx.x << 7;
  const u16* Ab = A + (size_t)blockIdx.z * sA;
  const u16* Bb = BT + (size_t)blockIdx.z * sB;
  int fr = lane & 15, kg = lane >> 4;
  int wr = wid >> 1, wc = wid & 1;
  int f0 = tid, f1 = tid + 256;
  const u16* pA0 = Ab + (size_t)(m0 + (f0 >> 2)) * K + (f0 & 3) * 8;
  const u16* pA1 = Ab + (size_t)(m0 + (f1 >> 2)) * K + (f1 & 3) * 8;
  const u16* pB0 = Bb + (size_t)(n0 + (f0 >> 2)) * K + (f0 & 3) * 8;
  const u16* pB1 = Bb + (size_t)(n0 + (f1 >> 2)) * K + (f1 & 3) * 8;
  u16* dA0 = &lsa[wid * 512];
  u16* dA1 = &lsa[(wid + 4) * 512];
  u16* dB0 = &lsb[wid * 512];
  u16* dB1 = &lsb[(wid + 4) * 512];
  f32x4 acc[4][4] = {};
  for (int kt = 0; kt < K; kt += 32) {
    gld_lds16(pA0, dA0); gld_lds16(pA1, dA1);
    gld_lds16(pB0, dB0); gld_lds16(pB1, dB1);
    pA0 += 32; pA1 += 32; pB0 += 32; pB1 += 32;
    __syncthreads();
    s16x8 af[4], bf_[4];
#pragma unroll
    for (int mi = 0; mi < 4; ++mi)
      af[mi] = *(const s16x8*)&lsa[(wr * 64 + mi * 16 + fr) * 32 + kg * 8];
#pragma unroll
    for (int ni = 0; ni < 4; ++ni)
      bf_[ni] = *(const s16x8*)&lsb[(wc * 64 + ni * 16 + fr) * 32 + kg * 8];
#pragma unroll
    for (int mi = 0; mi < 4; ++mi)
#pragma unroll
      for (int ni = 0; ni < 4; ++ni)
        acc[mi][ni] = __builtin_amdgcn_mfma_f32_16x16x32_bf16(af[mi], bf_[ni], acc[mi][ni], 0, 0, 0);
    __syncthreads();
  }
  int r0 = m0 + wr * 64 + kg * 4;
  int c0 = n0 + wc * 64 + fr;
  u16* C = Cv + (size_t)blockIdx.z * sC;
#pragma unroll
  for (int mi = 0; mi < 4; ++mi)
#pragma unroll
    for (int ni = 0; ni < 4; ++ni)
#pragma unroll
      for (int j = 0; j < 4; ++j)
        C[(size_t)(r0 + mi * 16 + j) * N + (c0 + ni * 16)] = f2bf(acc[mi][ni][j]);
}

// ---------------- 128x128 GEMM v3: TRIPLE-buffer LDS, depth-2 prefetch ----------------
// C[m][n] = sum_k A[m][k]*BT[n][k], K=512, strides 512, C-stride 8192.  4 waves, BK=32,
// LDS 3x(8KB A + 8KB B) = 48 KB -> 3 blocks/CU.
// R9 diagnosis: depth-1 prefetch gave tile k only ~1 iter (~300cy) to land vs ~600-900cy
// L3/HBM latency -> every K-step stalled in vmcnt.  Depth-2: at iter k issue stage(k+2);
// tile k has had TWO iterations to land.  vmcnt: 12 outstanding - oldest 4 (tile k) = 8.
// Swizzle (verified 0 conflicts): within each 128B double-row b2, logical (rl, chunk q)
// at phys slot (rl*4 + q + b2) & 7.  Linear gld_lds dest, inverse-permuted global src.
template <int OUTF>
__global__ __launch_bounds__(256, 3) void gemm128(
    const u16* __restrict__ A, size_t sA,
    const u16* __restrict__ BT, size_t sB,
    void* __restrict__ Cv, size_t sC,
    const float* __restrict__ bias,
    int Mt, int Nt)
{
  __shared__ u16 lsa[3][4096];
  __shared__ u16 lsb[3][4096];
  const int tid = threadIdx.x, wid = tid >> 6, lane = tid & 63;
  const int fr = lane & 15, kg = lane >> 4;
  const int wr = wid >> 1, wc = wid & 1;

  // T1: bijective XCD chunk swizzle (nwg % 8 == 0), M fastest -> same-XCD blocks share B panel
  const int nwg = (int)gridDim.x;
  const int bx = (int)blockIdx.x;
  const int id = (bx & 7) * (nwg >> 3) + (bx >> 3);
  const int my = id % Mt;
  const int t2 = id / Mt;
  const int nx = t2 % Nt;
  const int z  = t2 / Nt;
  const int m0 = my << 7, n0 = nx << 7;
  const u16* Ab = A + (size_t)z * sA;
  const u16* Bb = BT + (size_t)z * sB;

  // staging: thread covers phys 16B-chunks P0 = tid, P1 = tid+256 (512 chunks per 8KB tile).
  // phys chunk P: double-row b2 = P>>3, slot s = P&7 holds t = (s-b2)&7:
  //   row = b2*2 + (t>>2), within-row chunk = t&3.
  const int P0 = tid, P1 = tid + 256;
  int b2_, s_, t_;
  b2_ = P0 >> 3; s_ = P0 & 7; t_ = (s_ - b2_) & 7;
  const size_t g0 = (size_t)((b2_ << 1) + (t_ >> 2)) * 512 + (t_ & 3) * 8;
  b2_ = P1 >> 3; s_ = P1 & 7; t_ = (s_ - b2_) & 7;
  const size_t g1 = (size_t)((b2_ << 1) + (t_ >> 2)) * 512 + (t_ & 3) * 8;
  const u16* paG0 = Ab + (size_t)m0 * 512 + g0;
  const u16* paG1 = Ab + (size_t)m0 * 512 + g1;
  const u16* pbG0 = Bb + (size_t)n0 * 512 + g0;
  const u16* pbG1 = Bb + (size_t)n0 * 512 + g1;

  // frag LDS offsets (halves): row r, k-chunk kg -> (r>>1)*64 + (((r&1)*4 + kg + (r>>1))&7)*8
  int aoff[4], boff[4];
#pragma unroll
  for (int i = 0; i < 4; ++i) {
    int ra = wr * 64 + i * 16 + fr;
    aoff[i] = (ra >> 1) * 64 + ((((ra & 1) << 2) + kg + (ra >> 1)) & 7) * 8;
    int rb = wc * 64 + i * 16 + fr;
    boff[i] = (rb >> 1) * 64 + ((((rb & 1) << 2) + kg + (rb >> 1)) & 7) * 8;
  }

  auto stage = [&](int sl, int kt) {
    gld_lds16(paG0 + kt, &lsa[sl][P0 * 8]);
    gld_lds16(paG1 + kt, &lsa[sl][P1 * 8]);
    gld_lds16(pbG0 + kt, &lsb[sl][P0 * 8]);
    gld_lds16(pbG1 + kt, &lsb[sl][P1 * 8]);
  };

  f32x4 acc[4][4] = {};
  stage(0, 0);                                   // prologue: tiles 0,1 in flight (8 loads)
  stage(1, 32);
#pragma unroll
  for (int k = 0; k < 16; ++k) {
    if (k < 14) stage((k + 2) % 3, (k + 2) * 32);   // depth-2: issue tile k+2 (12 in flight)
    if (k < 14)      { asm volatile("s_waitcnt vmcnt(8)" ::: "memory"); }  // oldest 4 = tile k
    else if (k == 14){ asm volatile("s_waitcnt vmcnt(4)" ::: "memory"); }
    else             { asm volatile("s_waitcnt vmcnt(0)" ::: "memory"); }
    __builtin_amdgcn_s_barrier();                   // stage(k) visible to all waves
    s16x8 af[4], bf_[4];
    const u16* la = lsa[k % 3];
    const u16* lb = lsb[k % 3];
#pragma unroll
    for (int mi = 0; mi < 4; ++mi) af[mi] = dsr128(la + aoff[mi]);
#pragma unroll
    for (int ni = 0; ni < 4; ++ni) bf_[ni] = dsr128(lb + boff[ni]);
    asm volatile("s_waitcnt lgkmcnt(0)" ::: "memory");
    __builtin_amdgcn_sched_barrier(0);
    __builtin_amdgcn_s_setprio(1);
#pragma unroll
    for (int mi = 0; mi < 4; ++mi)
#pragma unroll
      for (int ni = 0; ni < 4; ++ni)
        acc[mi][ni] = __builtin_amdgcn_mfma_f32_16x16x32_bf16(af[mi], bf_[ni], acc[mi][ni], 0, 0, 0);
    __builtin_amdgcn_s_setprio(0);
    __builtin_amdgcn_s_barrier();                   // WAR gate: buf[(k+3)%3]=buf[k%3] may be re-staged at iter k+1
  }

  // epilogue: C/D frag layout col = lane&15, row = (lane>>4)*4 + j
  const int r0 = m0 + wr * 64 + kg * 4;
  const int c0 = n0 + wc * 64 + fr;
  if (OUTF == 0) {
    u16* C = (u16*)Cv + (size_t)z * sC;
#pragma unroll
    for (int mi = 0; mi < 4; ++mi)
#pragma unroll
      for (int ni = 0; ni < 4; ++ni)
#pragma unroll
        for (int j = 0; j < 4; ++j)
          C[(size_t)(r0 + mi * 16 + j) * 8192 + (c0 + ni * 16)] = f2bf(acc[mi][ni][j]);
  } else {
    float* C = (float*)Cv + (size_t)z * sC;
#pragma unroll
    for (int mi = 0; mi < 4; ++mi)
#pragma unroll
      for (int j = 0; j < 4; ++j) {
        float bv = bias[r0 + mi * 16 + j];
#pragma unroll
        for (int ni = 0; ni < 4; ++ni)
          C[(size_t)(r0 + mi * 16 + j) * 8192 + (c0 + ni * 16)] = acc[mi][ni][j] + bv;
      }
  }
}

// ---------------- context partials: per (split s, h, b): atomically accumulate
// E[b][h][d][e] += exp(k) @ v^T over L-slice, Z[b][h][d] += rowsum(exp(k))
#define NSPLIT 16
#define SLICE  512   // 8192 / NSPLIT
__global__ __launch_bounds__(256) void ctx_partial(const u16* __restrict__ kv,
                                                   float* __restrict__ E, float* __restrict__ Z) {
  int s = blockIdx.x, h = blockIdx.y, b = blockIdx.z;
  int tid = threadIdx.x, wid = tid >> 6, lane = tid & 63;
  int fr = lane & 15, kg = lane >> 4;
  const u16* kbase = kv + ((size_t)b * 1024 + h * 64) * 8192;          // k rows
  const u16* vbase = kbase + (size_t)512 * 8192;                        // v rows
  int d = wid * 16 + fr;                                                // A-frag row for this lane
  const u16* krow = kbase + (size_t)d * 8192 + s * SLICE + kg * 8;
  f32x4 acc[4] = {};
  float z = 0.f;
  for (int l = 0; l < SLICE; l += 32) {
    s16x8 kf = *(const s16x8*)(krow + l);
    s16x8 pf;
#pragma unroll
    for (int j = 0; j < 8; ++j) {
      float p = __expf(bf2f((u16)kf[j]));   // no max-subtraction: |k| <~ 6, exp safe in fp32
      z += p;
      pf[j] = (short)f2bf(p);
    }
#pragma unroll
    for (int ni = 0; ni < 4; ++ni) {
      int e = ni * 16 + fr;
      const s16x8 vf = *(const s16x8*)(vbase + (size_t)e * 8192 + s * SLICE + kg * 8 + l);
      acc[ni] = __builtin_amdgcn_mfma_f32_16x16x32_bf16(pf, vf, acc[ni], 0, 0, 0);
    }
  }
  z += __shfl_xor(z, 16);
  z += __shfl_xor(z, 32);
  size_t bh = (size_t)(b * 8 + h);
  if (kg == 0) atomicAdd(&Z[bh * 64 + d], z);
  float* Eb = E + bh * 4096;
#pragma unroll
  for (int ni = 0; ni < 4; ++ni)
#pragma unroll
    for (int j = 0; j < 4; ++j)
      atomicAdd(&Eb[(wid * 16 + kg * 4 + j) * 64 + ni * 16 + fr], acc[ni][j]);  // C/D: col=l&15, row=(l>>4)*4+j
}

// ---------------- normalize ctx + M1[b][c][h*64+d] = sum_e Wout[c][h*64+e]*ctx[d][e]
__global__ __launch_bounds__(256) void m1_fused(const float* __restrict__ E, const float* __restrict__ Z,
                                                const u16* __restrict__ Wout, u16* __restrict__ M1) {
  int cb = blockIdx.x, h = blockIdx.y, b = blockIdx.z;
  __shared__ float ctx[64][65];
  __shared__ float zs[64];
  int tid = threadIdx.x;
  size_t bh = (size_t)(b * 8 + h);
  const float* Eb = E + bh * 4096;
  if (tid < 64) zs[tid] = Z[bh * 64 + tid];
  __syncthreads();
  for (int i = tid; i < 4096; i += 256)
    ctx[i >> 6][i & 63] = Eb[i] / zs[i >> 6];
  __syncthreads();
  int d = tid & 63;
  int hbase = h * 64;
  for (int ci = 0; ci < 16; ++ci) {
    int c = __builtin_amdgcn_readfirstlane(cb * 64 + (tid >> 6) + ci * 4);  // wave-uniform -> SGPR
    const u16* wrow = Wout + c * 512 + hbase;
    float a0 = 0.f, a1 = 0.f, a2 = 0.f, a3 = 0.f;
#pragma unroll
    for (int e = 0; e < 64; e += 4) {
      a0 += bf2f(wrow[e + 0]) * ctx[d][e + 0];
      a1 += bf2f(wrow[e + 1]) * ctx[d][e + 1];
      a2 += bf2f(wrow[e + 2]) * ctx[d][e + 2];
      a3 += bf2f(wrow[e + 3]) * ctx[d][e + 3];
    }
    M1[((size_t)b * 512 + c) * 512 + hbase + d] = f2bf((a0 + a1) + (a2 + a3));
  }
}

extern "C" void kernel_launch(void* const* d_in, const int* in_sizes, int n_in,
                              void* d_out, int out_size, void* d_ws, size_t ws_size,
                              hipStream_t stream) {
  const float* x     = (const float*)d_in[0];   // [8,512,8192]
  const float* Wqkv  = (const float*)d_in[1];   // [1536,512]
  const float* Woutf = (const float*)d_in[2];   // [512,512]
  const float* bout  = (const float*)d_in[3];   // [512]
  char* ws = (char*)d_ws;
  u16*  xt  = (u16*)ws;                          //  64 MB  xt[b][l][c] bf16
  u16*  kv  = (u16*)(ws + 67108864);             // 128 MB  kv[b][o<1024][l] bf16 (k rows 0..511, v rows 512..1023)
  u16*  Wkv = (u16*)(ws + 201326592);            //   1 MB
  u16*  WqT = (u16*)(ws + 202375168);            // 0.5 MB
  u16*  Wo  = (u16*)(ws + 202899456);            // 0.5 MB
  u16*  M1  = (u16*)(ws + 203423744);            //   4 MB
  u16*  G   = (u16*)(ws + 207618048);            //   4 MB
  float* E  = (float*)(ws + 211812352);          //   1 MB  E[b][h][64][64] f32 (atomic-accumulated)
  float* Z  = (float*)(ws + 212860928);          //  16 KB  Z[b][h][64] f32

  hipMemsetAsync(ws + 211812352, 0, 1048576 + 16384, stream);  // zero E+Z (ws not re-poisoned between replays)
  prep_w<<<2048, 256, 0, stream>>>(Wqkv, Woutf, Wkv, WqT, Wo);
  prep_x<<<dim3(256, 16, 8), 256, 0, stream>>>(x, xt);
  // kv[b] = Wkv @ x[b] : M=1024, N=8192, K=512  (grid = Mt*Nt*B = 8*64*8 = 4096)
  gemm128<0><<<4096, 256, 0, stream>>>(Wkv, 0, xt, (size_t)8192 * 512,
                                       kv, (size_t)1024 * 8192, nullptr, 8, 64);
  ctx_partial<<<dim3(NSPLIT, 8, 8), 256, 0, stream>>>(kv, E, Z);
  m1_fused<<<dim3(8, 8, 8), 256, 0, stream>>>(E, Z, Wo, M1);
  // G[b] = M1[b] @ Wq : M=512, N=512, K=512   (small: old 128² kernel)
  gemm_bt<<<dim3(4, 4, 8), 256, 0, stream>>>(M1, (size_t)512 * 512, WqT, 0,
                                             G, (size_t)512 * 512, 512, 512);
  // out[b] = G[b] @ x[b] + b_out : M=512, N=8192, K=512, f32 out + bias  (grid = 4*64*8 = 2048)
  gemm128<1><<<2048, 256, 0, stream>>>(G, (size_t)512 * 512, xt, (size_t)8192 * 512,
                                       d_out, (size_t)512 * 8192, bout, 4, 64);
}

// Round 11
// 227.994 us; speedup vs baseline: 1.2244x; 1.1924x over previous
//
#include <hip/hip_runtime.h>
#include <hip/hip_bf16.h>

typedef unsigned short u16;
typedef __attribute__((ext_vector_type(8))) short s16x8;   // 8 bf16 (4 VGPRs) MFMA A/B frag
typedef __attribute__((ext_vector_type(4))) float f32x4;   // MFMA C/D frag

__device__ __forceinline__ u16 f2bf(float f) {
  union { float f; unsigned u; } v; v.f = f;
  unsigned r = (v.u + 0x7fffu + ((v.u >> 16) & 1u)) >> 16;  // RNE
  return (u16)r;
}
__device__ __forceinline__ float bf2f(u16 u) {
  union { unsigned u; float f; } v; v.u = ((unsigned)u) << 16;
  return v.f;
}
__device__ __forceinline__ void gld_lds16(const void* g, void* l) {
  __builtin_amdgcn_global_load_lds(
      (const __attribute__((address_space(1))) void*)g,
      (__attribute__((address_space(3))) void*)l, 16, 0, 0);
}
// inline-asm ds_read_b128 (numerics proven R7); pair with lgkmcnt(0)+sched_barrier(0) (rule 18)
__device__ __forceinline__ s16x8 dsr128(const u16* p) {
  s16x8 r;
  asm volatile("ds_read_b128 %0, %1"
               : "=v"(r)
               : "v"((const __attribute__((address_space(3))) u16*)p));
  return r;
}

// ---------------- weight prep ----------------
// Wkv2 bf16 [1024][512] HEAD-MAJOR: row h*128+r = k-row(h,r) for r<64, v-row(h,r-64) for r>=64.
// WqT bf16 [512(c)][512(hd)], Wout bf16 [512][512].
__global__ void prep_w(const float* __restrict__ Wqkv, const float* __restrict__ Woutf,
                       u16* __restrict__ Wkv2, u16* __restrict__ WqT, u16* __restrict__ Wout) {
  int i = blockIdx.x * 256 + threadIdx.x;          // grid 2048*256 = 524288
  {
    int o = i >> 9, c = i & 511;
    int h = o >> 7, r = o & 127;
    int src = (r < 64) ? (512 + h * 64 + r) : (1024 + h * 64 + (r - 64));
    Wkv2[i] = f2bf(Wqkv[src * 512 + c]);
  }
  if (i < 262144) {
    int c = i >> 9, o = i & 511;
    WqT[i]  = f2bf(Wqkv[o * 512 + c]);             // WqT[c][hd] = Wq[hd][c]
    Wout[i] = f2bf(Woutf[i]);
  }
}

// ---------------- x transpose+convert: x[b][c][l] f32 -> xt[b][l][c] bf16
__global__ __launch_bounds__(256) void prep_x(const float* __restrict__ x, u16* __restrict__ xt) {
  __shared__ float t[32][33];
  int l0 = blockIdx.x * 32, c0 = blockIdx.y * 32;
  size_t b = blockIdx.z;
  int tid = threadIdx.x;
  int r = tid >> 3, q = tid & 7;
  const float4 v = *(const float4*)(x + (b * 512 + c0 + r) * 8192 + l0 + q * 4);
  t[r][q * 4 + 0] = v.x; t[r][q * 4 + 1] = v.y;
  t[r][q * 4 + 2] = v.z; t[r][q * 4 + 3] = v.w;
  __syncthreads();
  ushort4 o;
  o.x = f2bf(t[q * 4 + 0][r]); o.y = f2bf(t[q * 4 + 1][r]);
  o.z = f2bf(t[q * 4 + 2][r]); o.w = f2bf(t[q * 4 + 3][r]);
  *(ushort4*)(xt + (b * 8192 + l0 + r) * 512 + c0 + q * 4) = o;
}

// ---------------- small-GEMM (m97-style 128x128, BK=32, linear LDS): bf16 out
__global__ __launch_bounds__(256) void gemm_bt(
    const u16* __restrict__ A, size_t sA,
    const u16* __restrict__ BT, size_t sB,
    u16* __restrict__ Cv, size_t sC,
    int N, int K)
{
  __shared__ u16 lsa[128 * 32];
  __shared__ u16 lsb[128 * 32];
  int tid = threadIdx.x, wid = tid >> 6, lane = tid & 63;
  int m0 = blockIdx.y << 7, n0 = blockIdx.x << 7;
  const u16* Ab = A + (size_t)blockIdx.z * sA;
  const u16* Bb = BT + (size_t)blockIdx.z * sB;
  int fr = lane & 15, kg = lane >> 4;
  int wr = wid >> 1, wc = wid & 1;
  int f0 = tid, f1 = tid + 256;
  const u16* pA0 = Ab + (size_t)(m0 + (f0 >> 2)) * K + (f0 & 3) * 8;
  const u16* pA1 = Ab + (size_t)(m0 + (f1 >> 2)) * K + (f1 & 3) * 8;
  const u16* pB0 = Bb + (size_t)(n0 + (f0 >> 2)) * K + (f0 & 3) * 8;
  const u16* pB1 = Bb + (size_t)(n0 + (f1 >> 2)) * K + (f1 & 3) * 8;
  u16* dA0 = &lsa[wid * 512];
  u16* dA1 = &lsa[(wid + 4) * 512];
  u16* dB0 = &lsb[wid * 512];
  u16* dB1 = &lsb[(wid + 4) * 512];
  f32x4 acc[4][4] = {};
  for (int kt = 0; kt < K; kt += 32) {
    gld_lds16(pA0, dA0); gld_lds16(pA1, dA1);
    gld_lds16(pB0, dB0); gld_lds16(pB1, dB1);
    pA0 += 32; pA1 += 32; pB0 += 32; pB1 += 32;
    __syncthreads();
    s16x8 af[4], bf_[4];
#pragma unroll
    for (int mi = 0; mi < 4; ++mi)
      af[mi] = *(const s16x8*)&lsa[(wr * 64 + mi * 16 + fr) * 32 + kg * 8];
#pragma unroll
    for (int ni = 0; ni < 4; ++ni)
      bf_[ni] = *(const s16x8*)&lsb[(wc * 64 + ni * 16 + fr) * 32 + kg * 8];
#pragma unroll
    for (int mi = 0; mi < 4; ++mi)
#pragma unroll
      for (int ni = 0; ni < 4; ++ni)
        acc[mi][ni] = __builtin_amdgcn_mfma_f32_16x16x32_bf16(af[mi], bf_[ni], acc[mi][ni], 0, 0, 0);
    __syncthreads();
  }
  int r0 = m0 + wr * 64 + kg * 4;
  int c0 = n0 + wc * 64 + fr;
  u16* C = Cv + (size_t)blockIdx.z * sC;
#pragma unroll
  for (int mi = 0; mi < 4; ++mi)
#pragma unroll
    for (int ni = 0; ni < 4; ++ni)
#pragma unroll
      for (int j = 0; j < 4; ++j)
        C[(size_t)(r0 + mi * 16 + j) * N + (c0 + ni * 16)] = f2bf(acc[mi][ni][j]);
}

// ---------------- FUSED kv-GEMM + context ----------------
// Block = (head h = Mt-idx, L-slice nx, batch z).  Main loop: R10's verified 128x128 BK=32
// triple-buffer GEMM computing [64 k-rows; 64 v-rows] x 128 L.  Epilogue (replaces C-write):
// exp(k)->kbuf, v->vbuf (LDS, padded stride 136), Z row-sums, E-tile = kbuf @ vbuf^T over
// l=128 via MFMA, atomicAdd into E[bh][64][64].  kv NEVER touches HBM (-131MB W, -128MB R).
__global__ __launch_bounds__(256, 3) void gemm_ctx(
    const u16* __restrict__ A,             // Wkv2 [1024][512], head-major
    const u16* __restrict__ BT, size_t sB, // xt
    float* __restrict__ E, float* __restrict__ Z)
{
  __shared__ u16 pool[24576];   // main loop: lsa sl at sl*4096, lsb at 12288+sl*4096 (48KB)
  const int tid = threadIdx.x, wid = tid >> 6, lane = tid & 63;
  const int fr = lane & 15, kg = lane >> 4;
  const int wr = wid >> 1, wc = wid & 1;

  const int nwg = (int)gridDim.x;                  // 4096
  const int bx = (int)blockIdx.x;
  const int id = (bx & 7) * (nwg >> 3) + (bx >> 3);
  const int my = id % 8;                            // head
  const int t2 = id / 8;
  const int nx = t2 % 64;
  const int z  = t2 / 64;
  const int m0 = my << 7, n0 = nx << 7;
  const u16* Ab = A + (size_t)m0 * 512;
  const u16* Bb = BT + (size_t)z * sB + (size_t)n0 * 512;

  // staging swizzle (verified 0-conflict): phys chunk P: b2=P>>3, slot s holds t=(s-b2)&7:
  // row = b2*2 + (t>>2), chunk = t&3
  const int P0 = tid, P1 = tid + 256;
  int b2_, s_, t_;
  b2_ = P0 >> 3; s_ = P0 & 7; t_ = (s_ - b2_) & 7;
  const size_t g0 = (size_t)((b2_ << 1) + (t_ >> 2)) * 512 + (t_ & 3) * 8;
  b2_ = P1 >> 3; s_ = P1 & 7; t_ = (s_ - b2_) & 7;
  const size_t g1 = (size_t)((b2_ << 1) + (t_ >> 2)) * 512 + (t_ & 3) * 8;

  int aoff[4], boff[4];
#pragma unroll
  for (int i = 0; i < 4; ++i) {
    int ra = wr * 64 + i * 16 + fr;
    aoff[i] = (ra >> 1) * 64 + ((((ra & 1) << 2) + kg + (ra >> 1)) & 7) * 8;
    int rb = wc * 64 + i * 16 + fr;
    boff[i] = (rb >> 1) * 64 + ((((rb & 1) << 2) + kg + (rb >> 1)) & 7) * 8;
  }

  auto stage = [&](int sl, int kt) {
    gld_lds16(Ab + g0 + kt, &pool[sl * 4096 + P0 * 8]);
    gld_lds16(Ab + g1 + kt, &pool[sl * 4096 + P1 * 8]);
    gld_lds16(Bb + g0 + kt, &pool[12288 + sl * 4096 + P0 * 8]);
    gld_lds16(Bb + g1 + kt, &pool[12288 + sl * 4096 + P1 * 8]);
  };

  f32x4 acc[4][4] = {};
  stage(0, 0);
  stage(1, 32);
#pragma unroll
  for (int k = 0; k < 16; ++k) {
    if (k < 14) stage((k + 2) % 3, (k + 2) * 32);
    if (k < 14)      { asm volatile("s_waitcnt vmcnt(8)" ::: "memory"); }
    else if (k == 14){ asm volatile("s_waitcnt vmcnt(4)" ::: "memory"); }
    else             { asm volatile("s_waitcnt vmcnt(0)" ::: "memory"); }
    __builtin_amdgcn_s_barrier();
    s16x8 af[4], bf_[4];
    const u16* la = &pool[(k % 3) * 4096];
    const u16* lb = &pool[12288 + (k % 3) * 4096];
#pragma unroll
    for (int mi = 0; mi < 4; ++mi) af[mi] = dsr128(la + aoff[mi]);
#pragma unroll
    for (int ni = 0; ni < 4; ++ni) bf_[ni] = dsr128(lb + boff[ni]);
    asm volatile("s_waitcnt lgkmcnt(0)" ::: "memory");
    __builtin_amdgcn_sched_barrier(0);
    __builtin_amdgcn_s_setprio(1);
#pragma unroll
    for (int mi = 0; mi < 4; ++mi)
#pragma unroll
      for (int ni = 0; ni < 4; ++ni)
        acc[mi][ni] = __builtin_amdgcn_mfma_f32_16x16x32_bf16(af[mi], bf_[ni], acc[mi][ni], 0, 0, 0);
    __builtin_amdgcn_s_setprio(0);
    __builtin_amdgcn_s_barrier();
  }

  // ---------- fused ctx epilogue ----------
  const size_t bh = (size_t)z * 8 + my;
  u16* kbuf = pool;                 // [64][136] bf16 (17408 u16 <= 24576)
  u16* vbuf = pool + 64 * 136;
  // write exp(k) (wr==0) / v (wr==1) tiles into LDS, row-padded stride 136
#pragma unroll
  for (int mi = 0; mi < 4; ++mi)
#pragma unroll
    for (int ni = 0; ni < 4; ++ni)
#pragma unroll
      for (int j = 0; j < 4; ++j) {
        int r = mi * 16 + kg * 4 + j;              // local row (d or e), C/D layout
        int l = wc * 64 + ni * 16 + fr;
        float vv = acc[mi][ni][j];
        if (wr == 0) kbuf[r * 136 + l] = f2bf(__expf(vv));   // |k|<~6, exp safe
        else         vbuf[r * 136 + l] = f2bf(vv);
      }
  __syncthreads();
  // Z[d] += sum_l exp(k[d][l]) over this L-slice
  {
    int d = tid >> 2, q = tid & 3;
    float s = 0.f;
#pragma unroll
    for (int i = 0; i < 4; ++i) {
      s16x8 k8 = *(const s16x8*)&kbuf[d * 136 + q * 32 + i * 8];
#pragma unroll
      for (int j = 0; j < 8; ++j) s += bf2f((u16)k8[j]);
    }
    s += __shfl_xor(s, 1);
    s += __shfl_xor(s, 2);
    if (q == 0) atomicAdd(&Z[bh * 64 + d], s);
  }
  // E[d][e] += sum_l expk[d][l]*v[e][l]; wave wid owns d-rows [wid*16, wid*16+16)
  f32x4 eacc[4] = {};
#pragma unroll
  for (int ks = 0; ks < 4; ++ks) {
    s16x8 ka = *(const s16x8*)&kbuf[(wid * 16 + fr) * 136 + ks * 32 + kg * 8];
#pragma unroll
    for (int n2 = 0; n2 < 4; ++n2) {
      s16x8 vb = *(const s16x8*)&vbuf[(n2 * 16 + fr) * 136 + ks * 32 + kg * 8];
      eacc[n2] = __builtin_amdgcn_mfma_f32_16x16x32_bf16(ka, vb, eacc[n2], 0, 0, 0);
    }
  }
  float* Eb = E + bh * 4096;
#pragma unroll
  for (int n2 = 0; n2 < 4; ++n2)
#pragma unroll
    for (int j = 0; j < 4; ++j)
      atomicAdd(&Eb[(wid * 16 + kg * 4 + j) * 64 + n2 * 16 + fr], eacc[n2][j]);
}

// ---------------- 128x128 GEMM v3 (R10): triple-buffer, depth-2 prefetch; f32 out + bias
__global__ __launch_bounds__(256, 3) void gemm128f(
    const u16* __restrict__ A, size_t sA,
    const u16* __restrict__ BT, size_t sB,
    float* __restrict__ Cv, size_t sC,
    const float* __restrict__ bias,
    int Mt, int Nt)
{
  __shared__ u16 lsa[3][4096];
  __shared__ u16 lsb[3][4096];
  const int tid = threadIdx.x, wid = tid >> 6, lane = tid & 63;
  const int fr = lane & 15, kg = lane >> 4;
  const int wr = wid >> 1, wc = wid & 1;

  const int nwg = (int)gridDim.x;
  const int bx = (int)blockIdx.x;
  const int id = (bx & 7) * (nwg >> 3) + (bx >> 3);
  const int my = id % Mt;
  const int t2 = id / Mt;
  const int nx = t2 % Nt;
  const int z  = t2 / Nt;
  const int m0 = my << 7, n0 = nx << 7;
  const u16* Ab = A + (size_t)z * sA;
  const u16* Bb = BT + (size_t)z * sB;

  const int P0 = tid, P1 = tid + 256;
  int b2_, s_, t_;
  b2_ = P0 >> 3; s_ = P0 & 7; t_ = (s_ - b2_) & 7;
  const size_t g0 = (size_t)((b2_ << 1) + (t_ >> 2)) * 512 + (t_ & 3) * 8;
  b2_ = P1 >> 3; s_ = P1 & 7; t_ = (s_ - b2_) & 7;
  const size_t g1 = (size_t)((b2_ << 1) + (t_ >> 2)) * 512 + (t_ & 3) * 8;
  const u16* paG0 = Ab + (size_t)m0 * 512 + g0;
  const u16* paG1 = Ab + (size_t)m0 * 512 + g1;
  const u16* pbG0 = Bb + (size_t)n0 * 512 + g0;
  const u16* pbG1 = Bb + (size_t)n0 * 512 + g1;

  int aoff[4], boff[4];
#pragma unroll
  for (int i = 0; i < 4; ++i) {
    int ra = wr * 64 + i * 16 + fr;
    aoff[i] = (ra >> 1) * 64 + ((((ra & 1) << 2) + kg + (ra >> 1)) & 7) * 8;
    int rb = wc * 64 + i * 16 + fr;
    boff[i] = (rb >> 1) * 64 + ((((rb & 1) << 2) + kg + (rb >> 1)) & 7) * 8;
  }

  auto stage = [&](int sl, int kt) {
    gld_lds16(paG0 + kt, &lsa[sl][P0 * 8]);
    gld_lds16(paG1 + kt, &lsa[sl][P1 * 8]);
    gld_lds16(pbG0 + kt, &lsb[sl][P0 * 8]);
    gld_lds16(pbG1 + kt, &lsb[sl][P1 * 8]);
  };

  f32x4 acc[4][4] = {};
  stage(0, 0);
  stage(1, 32);
#pragma unroll
  for (int k = 0; k < 16; ++k) {
    if (k < 14) stage((k + 2) % 3, (k + 2) * 32);
    if (k < 14)      { asm volatile("s_waitcnt vmcnt(8)" ::: "memory"); }
    else if (k == 14){ asm volatile("s_waitcnt vmcnt(4)" ::: "memory"); }
    else             { asm volatile("s_waitcnt vmcnt(0)" ::: "memory"); }
    __builtin_amdgcn_s_barrier();
    s16x8 af[4], bf_[4];
    const u16* la = lsa[k % 3];
    const u16* lb = lsb[k % 3];
#pragma unroll
    for (int mi = 0; mi < 4; ++mi) af[mi] = dsr128(la + aoff[mi]);
#pragma unroll
    for (int ni = 0; ni < 4; ++ni) bf_[ni] = dsr128(lb + boff[ni]);
    asm volatile("s_waitcnt lgkmcnt(0)" ::: "memory");
    __builtin_amdgcn_sched_barrier(0);
    __builtin_amdgcn_s_setprio(1);
#pragma unroll
    for (int mi = 0; mi < 4; ++mi)
#pragma unroll
      for (int ni = 0; ni < 4; ++ni)
        acc[mi][ni] = __builtin_amdgcn_mfma_f32_16x16x32_bf16(af[mi], bf_[ni], acc[mi][ni], 0, 0, 0);
    __builtin_amdgcn_s_setprio(0);
    __builtin_amdgcn_s_barrier();
  }

  const int r0 = m0 + wr * 64 + kg * 4;
  const int c0 = n0 + wc * 64 + fr;
  float* C = Cv + (size_t)z * sC;
#pragma unroll
  for (int mi = 0; mi < 4; ++mi)
#pragma unroll
    for (int j = 0; j < 4; ++j) {
      float bv = bias[r0 + mi * 16 + j];
#pragma unroll
      for (int ni = 0; ni < 4; ++ni)
        C[(size_t)(r0 + mi * 16 + j) * 8192 + (c0 + ni * 16)] = acc[mi][ni][j] + bv;
    }
}

// ---------------- normalize ctx + M1[b][c][h*64+d] = sum_e Wout[c][h*64+e]*ctx[d][e]
__global__ __launch_bounds__(256) void m1_fused(const float* __restrict__ E, const float* __restrict__ Z,
                                                const u16* __restrict__ Wout, u16* __restrict__ M1) {
  int cb = blockIdx.x, h = blockIdx.y, b = blockIdx.z;
  __shared__ float ctx[64][65];
  __shared__ float zs[64];
  int tid = threadIdx.x;
  size_t bh = (size_t)(b * 8 + h);
  const float* Eb = E + bh * 4096;
  if (tid < 64) zs[tid] = Z[bh * 64 + tid];
  __syncthreads();
  for (int i = tid; i < 4096; i += 256)
    ctx[i >> 6][i & 63] = Eb[i] / zs[i >> 6];
  __syncthreads();
  int d = tid & 63;
  int hbase = h * 64;
  for (int ci = 0; ci < 16; ++ci) {
    int c = __builtin_amdgcn_readfirstlane(cb * 64 + (tid >> 6) + ci * 4);  // wave-uniform -> SGPR
    const u16* wrow = Wout + c * 512 + hbase;
    float a0 = 0.f, a1 = 0.f, a2 = 0.f, a3 = 0.f;
#pragma unroll
    for (int e = 0; e < 64; e += 4) {
      a0 += bf2f(wrow[e + 0]) * ctx[d][e + 0];
      a1 += bf2f(wrow[e + 1]) * ctx[d][e + 1];
      a2 += bf2f(wrow[e + 2]) * ctx[d][e + 2];
      a3 += bf2f(wrow[e + 3]) * ctx[d][e + 3];
    }
    M1[((size_t)b * 512 + c) * 512 + hbase + d] = f2bf((a0 + a1) + (a2 + a3));
  }
}

extern "C" void kernel_launch(void* const* d_in, const int* in_sizes, int n_in,
                              void* d_out, int out_size, void* d_ws, size_t ws_size,
                              hipStream_t stream) {
  const float* x     = (const float*)d_in[0];   // [8,512,8192]
  const float* Wqkv  = (const float*)d_in[1];   // [1536,512]
  const float* Woutf = (const float*)d_in[2];   // [512,512]
  const float* bout  = (const float*)d_in[3];   // [512]
  char* ws = (char*)d_ws;
  u16*  xt  = (u16*)ws;                          //  64 MB  xt[b][l][c] bf16
  u16*  Wkv2= (u16*)(ws + 201326592);            //   1 MB  head-major {k,v}
  u16*  WqT = (u16*)(ws + 202375168);            // 0.5 MB
  u16*  Wo  = (u16*)(ws + 202899456);            // 0.5 MB
  u16*  M1  = (u16*)(ws + 203423744);            //   4 MB
  u16*  G   = (u16*)(ws + 207618048);            //   4 MB
  float* E  = (float*)(ws + 211812352);          //   1 MB  E[b][h][64][64] f32 (atomic)
  float* Z  = (float*)(ws + 212860928);          //  16 KB  Z[b][h][64] f32

  hipMemsetAsync(ws + 211812352, 0, 1048576 + 16384, stream);  // zero E+Z (ws not re-poisoned)
  prep_w<<<2048, 256, 0, stream>>>(Wqkv, Woutf, Wkv2, WqT, Wo);
  prep_x<<<dim3(256, 16, 8), 256, 0, stream>>>(x, xt);
  // fused kv GEMM + ctx: grid = 8 heads * 64 L-tiles * 8 b = 4096
  gemm_ctx<<<4096, 256, 0, stream>>>(Wkv2, xt, (size_t)8192 * 512, E, Z);
  m1_fused<<<dim3(8, 8, 8), 256, 0, stream>>>(E, Z, Wo, M1);
  // G[b] = M1[b] @ Wq : 512^3 (small)
  gemm_bt<<<dim3(4, 4, 8), 256, 0, stream>>>(M1, (size_t)512 * 512, WqT, 0,
                                             G, (size_t)512 * 512, 512, 512);
  // out[b] = G[b] @ x[b] + b_out : M=512, N=8192, K=512, f32 out + bias
  gemm128f<<<2048, 256, 0, stream>>>(G, (size_t)512 * 512, xt, (size_t)8192 * 512,
                                     (float*)d_out, (size_t)512 * 8192, bout, 4, 64);
}